// Round 1
// baseline (3587.501 us; speedup 1.0000x reference)
//
#include <hip/hip_runtime.h>
#include <math.h>

#define MROWS 16384   // B*N
#define DIMD  512
#define KCOD  8192

// ---------------- ws layout (bytes) ----------------
// xsq    f32 [16384]       off 0        (65536)
// wsq    f32 [8192]        off 65536    (32768)
// idx    i32 [16384]       off 98304    (65536)
// partm  f32 [2][16384]    off 163840   (131072)
// parti  i32 [2][16384]    off 294912   (131072)
// partial f64 [8192]       off 425984   (65536)   -> total 491520 B

__global__ __launch_bounds__(256) void sqnorms_k(const float* __restrict__ A,
                                                 const float* __restrict__ W,
                                                 float* __restrict__ xsq,
                                                 float* __restrict__ wsq)
{
    const int lane = threadIdx.x & 63;
    const int wid  = (blockIdx.x * blockDim.x + threadIdx.x) >> 6;
    const int nw   = (gridDim.x * blockDim.x) >> 6;
    for (int r = wid; r < MROWS + KCOD; r += nw) {
        const float4* src = (const float4*)((r < MROWS) ? (A + (size_t)r * DIMD)
                                                        : (W + (size_t)(r - MROWS) * DIMD));
        float4 v0 = src[lane];
        float4 v1 = src[lane + 64];
        float s = v0.x*v0.x + v0.y*v0.y + v0.z*v0.z + v0.w*v0.w
                + v1.x*v1.x + v1.y*v1.y + v1.z*v1.z + v1.w*v1.w;
        #pragma unroll
        for (int m = 1; m < 64; m <<= 1) s += __shfl_xor(s, m, 64);
        if (lane == 0) { if (r < MROWS) xsq[r] = s; else wsq[r - MROWS] = s; }
    }
}

// Main: per block: 128 rows x 4096 codes (K-split 2). 512 threads.
// Per-thread 4 rows x 4 codes, fp64 accumulation (fp32 products are exact in fp64).
// dist = fl32( fl32(xsq + wsq) - 2*fl32(dot) )  -- emulates the reference fp32 formula,
// with the dot effectively exact. First-index tie-break everywhere.
__global__ __launch_bounds__(512) void vqmain_k(const float* __restrict__ A,
                                                const float* __restrict__ W,
                                                const float* __restrict__ xsq,
                                                const float* __restrict__ wsq,
                                                float* __restrict__ partm,
                                                int* __restrict__ parti)
{
    __shared__ double As[32][128];   // [d][row]
    __shared__ double Bs[32][64];    // [d][code]

    const int t   = threadIdx.x;
    const int tx  = t & 15;          // code group 0..15
    const int ty  = t >> 4;          // row group 0..31
    const int r0  = blockIdx.x * 128;
    const int kbase = blockIdx.y * 4096;

    // staging assignment (conflict-free LDS writes: consecutive lanes -> consecutive rows)
    const int a_row = t & 127;
    const int a_d   = (t >> 7) << 2;   // 0,4,8,12  (wave-uniform)
    const int w_row = t & 63;
    const int w_d   = (t >> 6) << 2;   // 0..28     (wave-uniform)

    const float* Abase = A + (size_t)(r0 + a_row) * DIMD + a_d;

    float xs[4];
    #pragma unroll
    for (int i = 0; i < 4; ++i) xs[i] = xsq[r0 + ty * 4 + i];

    float mbest[4]; int ibest[4];
    #pragma unroll
    for (int i = 0; i < 4; ++i) { mbest[i] = INFINITY; ibest[i] = 0; }

    // prefetch chunk (kt=0, dc=0)
    float4 av0 = *(const float4*)(Abase);
    float4 av1 = *(const float4*)(Abase + 16);
    float4 wv  = *(const float4*)(W + (size_t)(kbase + w_row) * DIMD + w_d);

    for (int kt = 0; kt < 64; ++kt) {
        double acc[4][4];
        #pragma unroll
        for (int i = 0; i < 4; ++i)
            #pragma unroll
            for (int j = 0; j < 4; ++j) acc[i][j] = 0.0;

        for (int dc = 0; dc < 16; ++dc) {
            __syncthreads();                       // prior chunk fully consumed
            As[a_d + 0][a_row]  = (double)av0.x;
            As[a_d + 1][a_row]  = (double)av0.y;
            As[a_d + 2][a_row]  = (double)av0.z;
            As[a_d + 3][a_row]  = (double)av0.w;
            As[a_d + 16][a_row] = (double)av1.x;
            As[a_d + 17][a_row] = (double)av1.y;
            As[a_d + 18][a_row] = (double)av1.z;
            As[a_d + 19][a_row] = (double)av1.w;
            Bs[w_d + 0][w_row]  = (double)wv.x;
            Bs[w_d + 1][w_row]  = (double)wv.y;
            Bs[w_d + 2][w_row]  = (double)wv.z;
            Bs[w_d + 3][w_row]  = (double)wv.w;
            __syncthreads();

            // software-prefetch the next chunk (hidden under the 32-d FMA loop)
            int ndc = dc + 1, nkt = kt;
            if (ndc == 16) { ndc = 0; ++nkt; }
            if (nkt < 64) {
                av0 = *(const float4*)(Abase + ndc * 32);
                av1 = *(const float4*)(Abase + ndc * 32 + 16);
                wv  = *(const float4*)(W + (size_t)(kbase + nkt * 64 + w_row) * DIMD + ndc * 32 + w_d);
            }

            #pragma unroll 8
            for (int d = 0; d < 32; ++d) {
                double2 a01 = *(const double2*)&As[d][ty * 4];
                double2 a23 = *(const double2*)&As[d][ty * 4 + 2];
                double2 b01 = *(const double2*)&Bs[d][tx * 4];
                double2 b23 = *(const double2*)&Bs[d][tx * 4 + 2];
                acc[0][0] += a01.x * b01.x;  acc[0][1] += a01.x * b01.y;
                acc[0][2] += a01.x * b23.x;  acc[0][3] += a01.x * b23.y;
                acc[1][0] += a01.y * b01.x;  acc[1][1] += a01.y * b01.y;
                acc[1][2] += a01.y * b23.x;  acc[1][3] += a01.y * b23.y;
                acc[2][0] += a23.x * b01.x;  acc[2][1] += a23.x * b01.y;
                acc[2][2] += a23.x * b23.x;  acc[2][3] += a23.x * b23.y;
                acc[3][0] += a23.y * b01.x;  acc[3][1] += a23.y * b01.y;
                acc[3][2] += a23.y * b23.x;  acc[3][3] += a23.y * b23.y;
            }
        }

        const int k0 = kbase + kt * 64;
        #pragma unroll
        for (int i = 0; i < 4; ++i) {
            #pragma unroll
            for (int j = 0; j < 4; ++j) {
                const int k = k0 + tx * 4 + j;
                const float Df = (float)acc[i][j];                 // fl32(exact dot)
                const float dist = (xs[i] + wsq[k]) - 2.0f * Df;   // fl(fl(xsq+wsq) - 2D)
                if (dist < mbest[i]) { mbest[i] = dist; ibest[i] = k; }
            }
        }
    }

    // reduce across the 16 tx lanes (consecutive lanes within each wave)
    #pragma unroll
    for (int i = 0; i < 4; ++i) {
        float m = mbest[i]; int id = ibest[i];
        #pragma unroll
        for (int s = 1; s < 16; s <<= 1) {
            float om = __shfl_xor(m, s, 64);
            int   oi = __shfl_xor(id, s, 64);
            if (om < m || (om == m && oi < id)) { m = om; id = oi; }
        }
        if (tx == 0) {
            const int row = r0 + ty * 4 + i;
            partm[blockIdx.y * MROWS + row] = m;
            parti[blockIdx.y * MROWS + row] = id;
        }
    }
}

__global__ __launch_bounds__(256) void merge_k(const float* __restrict__ partm,
                                               const int* __restrict__ parti,
                                               int* __restrict__ idxo,
                                               float* __restrict__ out_ids)
{
    const int r = blockIdx.x * 256 + threadIdx.x;
    if (r >= MROWS) return;
    const float m0 = partm[r],       m1 = partm[MROWS + r];
    const int   i0 = parti[r],       i1 = parti[MROWS + r];
    // tie -> split 0 (lower indices) = first occurrence
    const int id = (m1 < m0) ? i1 : i0;
    idxo[r] = id;
    out_ids[r] = (float)id;
}

__global__ __launch_bounds__(256) void gather_k(const float* __restrict__ A,
                                                const float* __restrict__ W,
                                                const int* __restrict__ idx,
                                                float* __restrict__ out_zq,
                                                double* __restrict__ partial)
{
    __shared__ double wsum[4];
    const int t   = threadIdx.x;
    const int row = blockIdx.x * 2 + (t >> 7);
    const int col = t & 127;                       // float4 column
    const int id  = idx[row];
    const float4 ze = ((const float4*)(A + (size_t)row * DIMD))[col];
    const float4 zq = ((const float4*)(W + (size_t)id  * DIMD))[col];
    float4 o;
    o.x = ze.x + (zq.x - ze.x);
    o.y = ze.y + (zq.y - ze.y);
    o.z = ze.z + (zq.z - ze.z);
    o.w = ze.w + (zq.w - ze.w);
    ((float4*)(out_zq + (size_t)row * DIMD))[col] = o;
    const float dx = zq.x - ze.x, dy = zq.y - ze.y, dz = zq.z - ze.z, dw = zq.w - ze.w;
    double s = (double)dx*dx + (double)dy*dy + (double)dz*dz + (double)dw*dw;
    #pragma unroll
    for (int m = 1; m < 64; m <<= 1) s += __shfl_xor(s, m, 64);
    if ((t & 63) == 0) wsum[t >> 6] = s;
    __syncthreads();
    if (t == 0) partial[blockIdx.x] = (wsum[0] + wsum[1]) + (wsum[2] + wsum[3]);
}

__global__ __launch_bounds__(256) void fin_k(const double* __restrict__ partial,
                                             float* __restrict__ outs)
{
    __shared__ double wsum[4];
    const int t = threadIdx.x;
    double s = 0.0;
    for (int i = 0; i < 32; ++i) s += partial[t + 256 * i];
    #pragma unroll
    for (int m = 1; m < 64; m <<= 1) s += __shfl_xor(s, m, 64);
    if ((t & 63) == 0) wsum[t >> 6] = s;
    __syncthreads();
    if (t == 0) {
        const double tot = (wsum[0] + wsum[1]) + (wsum[2] + wsum[3]);
        const double mse = tot / (double)((size_t)MROWS * DIMD);
        const float mf = (float)mse;
        const float vq = (float)(mse * 1.25);   // codebook + 0.25*commit, identical means
        outs[0] = vq;     // vq_loss
        outs[1] = mf;     // codebook_loss
        outs[2] = mf;     // commit_loss
        outs[3] = 0.0f;   // orth_loss
        outs[4] = vq;     // loss_total
    }
}

extern "C" void kernel_launch(void* const* d_in, const int* in_sizes, int n_in,
                              void* d_out, int out_size, void* d_ws, size_t ws_size,
                              hipStream_t stream)
{
    const float* A = (const float*)d_in[0];   // z_e  [16384][512]
    const float* W = (const float*)d_in[1];   // W    [8192][512]

    char* ws = (char*)d_ws;
    float*  xsq     = (float*)(ws);
    float*  wsq     = (float*)(ws + 65536);
    int*    idx     = (int*)  (ws + 98304);
    float*  partm   = (float*)(ws + 163840);
    int*    parti   = (int*)  (ws + 294912);
    double* partial = (double*)(ws + 425984);

    float* out_zq  = (float*)d_out;
    float* out_ids = out_zq + (size_t)MROWS * DIMD;   // 8388608
    float* out_sc  = out_ids + MROWS;                 // 8404992

    hipLaunchKernelGGL(sqnorms_k, dim3(512), dim3(256), 0, stream, A, W, xsq, wsq);
    hipLaunchKernelGGL(vqmain_k,  dim3(128, 2), dim3(512), 0, stream, A, W, xsq, wsq, partm, parti);
    hipLaunchKernelGGL(merge_k,   dim3(64), dim3(256), 0, stream, partm, parti, idx, out_ids);
    hipLaunchKernelGGL(gather_k,  dim3(8192), dim3(256), 0, stream, A, W, idx, out_zq, partial);
    hipLaunchKernelGGL(fin_k,     dim3(1), dim3(256), 0, stream, partial, out_sc);
}

// Round 2
// 799.511 us; speedup vs baseline: 4.4871x; 4.4871x over previous
//
#include <hip/hip_runtime.h>
#include <math.h>

#define MROWS 16384   // B*N
#define DIMD  512
#define KCOD  8192
#define CAP   2097152u
#define MARGIN 9.0e-4f   // >= 2*worst-case bf16 dist err (7.4e-4) + tie window (1.3e-4)

typedef __attribute__((ext_vector_type(8))) short short8;
typedef __attribute__((ext_vector_type(4))) float f32x4;
typedef const __attribute__((address_space(1))) unsigned char glb_byte;
typedef __attribute__((address_space(3))) unsigned char lds_byte;

__device__ __forceinline__ void gload16(const void* g, void* l) {
    __builtin_amdgcn_global_load_lds((glb_byte*)g, (lds_byte*)l, 16, 0, 0);
}

__device__ __forceinline__ unsigned short f2bf(float f) {
    unsigned u = __float_as_uint(f);
    return (unsigned short)((u + 0x7FFFu + ((u >> 16) & 1u)) >> 16);   // RNE
}

// ---------------- fast-path ws layout (bytes) ----------------
#define OFF_ABF     0u           // bf16 [16384][512]  16MB
#define OFF_WBF     16777216u    // bf16 [8192][512]    8MB
#define OFF_XSQ     25165824u    // f32 [16384]
#define OFF_WSQ     25231360u    // f32 [8192]
#define OFF_ROWMIN  25264128u    // f32 [16384]
#define OFF_PARTMIN 25329664u    // f32 [16384][64]     4MB
#define OFF_RES     29523968u    // u64 [16384]
#define OFF_CNT     29655040u    // u32
#define OFF_LIST    29655296u    // u32 [CAP]           8MB
#define OFF_PARTIAL 38043904u    // f64 [8192]
#define OFF_IDX     38109440u    // i32 [16384]
#define WS_NEEDED   38174976u

// ===================== shared helpers (both paths) =====================

// EXACT same summation tree as round 1 (passed absmax 0) — do not change.
__global__ __launch_bounds__(256) void sqnorms_k(const float* __restrict__ A,
                                                 const float* __restrict__ W,
                                                 float* __restrict__ xsq,
                                                 float* __restrict__ wsq)
{
    const int lane = threadIdx.x & 63;
    const int wid  = (blockIdx.x * blockDim.x + threadIdx.x) >> 6;
    const int nw   = (gridDim.x * blockDim.x) >> 6;
    for (int r = wid; r < MROWS + KCOD; r += nw) {
        const float4* src = (const float4*)((r < MROWS) ? (A + (size_t)r * DIMD)
                                                        : (W + (size_t)(r - MROWS) * DIMD));
        float4 v0 = src[lane];
        float4 v1 = src[lane + 64];
        float s = v0.x*v0.x + v0.y*v0.y + v0.z*v0.z + v0.w*v0.w
                + v1.x*v1.x + v1.y*v1.y + v1.z*v1.z + v1.w*v1.w;
        #pragma unroll
        for (int m = 1; m < 64; m <<= 1) s += __shfl_xor(s, m, 64);
        if (lane == 0) { if (r < MROWS) xsq[r] = s; else wsq[r - MROWS] = s; }
    }
}

__global__ __launch_bounds__(256) void gather_k(const float* __restrict__ A,
                                                const float* __restrict__ W,
                                                const int* __restrict__ idx,
                                                float* __restrict__ out_zq,
                                                double* __restrict__ partial)
{
    __shared__ double wsum[4];
    const int t   = threadIdx.x;
    const int row = blockIdx.x * 2 + (t >> 7);
    const int col = t & 127;
    const int id  = idx[row];
    const float4 ze = ((const float4*)(A + (size_t)row * DIMD))[col];
    const float4 zq = ((const float4*)(W + (size_t)id  * DIMD))[col];
    float4 o;
    o.x = ze.x + (zq.x - ze.x);
    o.y = ze.y + (zq.y - ze.y);
    o.z = ze.z + (zq.z - ze.z);
    o.w = ze.w + (zq.w - ze.w);
    ((float4*)(out_zq + (size_t)row * DIMD))[col] = o;
    const float dx = zq.x - ze.x, dy = zq.y - ze.y, dz = zq.z - ze.z, dw = zq.w - ze.w;
    double s = (double)dx*dx + (double)dy*dy + (double)dz*dz + (double)dw*dw;
    #pragma unroll
    for (int m = 1; m < 64; m <<= 1) s += __shfl_xor(s, m, 64);
    if ((t & 63) == 0) wsum[t >> 6] = s;
    __syncthreads();
    if (t == 0) partial[blockIdx.x] = (wsum[0] + wsum[1]) + (wsum[2] + wsum[3]);
}

__global__ __launch_bounds__(256) void fin_k(const double* __restrict__ partial,
                                             float* __restrict__ outs)
{
    __shared__ double wsum[4];
    const int t = threadIdx.x;
    double s = 0.0;
    for (int i = 0; i < 32; ++i) s += partial[t + 256 * i];
    #pragma unroll
    for (int m = 1; m < 64; m <<= 1) s += __shfl_xor(s, m, 64);
    if ((t & 63) == 0) wsum[t >> 6] = s;
    __syncthreads();
    if (t == 0) {
        const double tot = (wsum[0] + wsum[1]) + (wsum[2] + wsum[3]);
        const double mse = tot / (double)((size_t)MROWS * DIMD);
        const float mf = (float)mse;
        const float vq = (float)(mse * 1.25);
        outs[0] = vq; outs[1] = mf; outs[2] = mf; outs[3] = 0.0f; outs[4] = vq;
    }
}

// ===================== fast path =====================

__global__ __launch_bounds__(256) void init_k(unsigned long long* __restrict__ res,
                                              unsigned int* __restrict__ gcount)
{
    const int i = blockIdx.x * 256 + threadIdx.x;
    if (i < MROWS) res[i] = ~0ull;
    if (i == 0) *gcount = 0u;
}

__global__ __launch_bounds__(256) void cvt_k(const float* __restrict__ A,
                                             const float* __restrict__ W,
                                             unsigned short* __restrict__ Abf,
                                             unsigned short* __restrict__ Wbf)
{
    const int NA4 = MROWS * DIMD / 4;      // 2097152
    const int NT4 = NA4 + KCOD * DIMD / 4; // 3145728
    for (int i = blockIdx.x * 256 + threadIdx.x; i < NT4; i += gridDim.x * 256) {
        float4 v;
        if (i < NA4) v = ((const float4*)A)[i];
        else         v = ((const float4*)W)[i - NA4];
        ushort4 o;
        o.x = f2bf(v.x); o.y = f2bf(v.y); o.z = f2bf(v.z); o.w = f2bf(v.w);
        if (i < NA4) ((ushort4*)Abf)[i] = o;
        else         ((ushort4*)Wbf)[i - NA4] = o;
    }
}

// bf16 MFMA GEMM, m97-style: 128x128 tile, K=512 in 16 chunks of 32,
// double-buffered LDS via global_load_lds width 16, 4 waves (2M x 2N),
// each wave 64x64 = 4x4 frags of 16x16x32.
// PASS 0: per-(row, code-tile) min of approx dist (wsq[k] - 2*dot).
// PASS 1: append candidates with approx dist <= rowmin + MARGIN.
template<int PASS>
__global__ __launch_bounds__(256) void vqgemm_k(
    const unsigned short* __restrict__ Abf,
    const unsigned short* __restrict__ Wbf,
    const float* __restrict__ wsq,
    const float* __restrict__ rowmin,
    float* __restrict__ partmin,
    unsigned int* __restrict__ list,
    unsigned int* __restrict__ gcount)
{
    __shared__ unsigned short As[2][4096];   // [buf][row*32 + k]
    __shared__ unsigned short Bs[2][4096];   // [buf][col*32 + k]
    __shared__ float aux_lds[256];           // PASS0: minbuf[2][128]; PASS1: rm[128]

    const int t    = threadIdx.x;
    const int lane = t & 63;
    const int w    = t >> 6;       // wave 0..3
    const int wm   = w >> 1, wn = w & 1;

    // XCD-chunked mapping: xcd gets 16 row-tiles x all 64 code-tiles,
    // consecutive j within an XCD shares the B-tile (L2-hot).
    const unsigned wg = blockIdx.x;
    const int xcd = wg & 7;
    const int j   = wg >> 3;
    const int rt  = xcd * 16 + (j & 15);
    const int ct  = j >> 4;
    const int r0  = rt * 128;
    const int c0  = ct * 128;

    if (PASS == 1 && t < 128) aux_lds[t] = rowmin[r0 + t] + MARGIN;

    // staging: 16 global_load_lds x 16B per chunk (4 per wave)
    const int inst0 = w * 2;
    const int lrow0 = inst0 * 16 + (lane >> 2);
    const int kof   = (lane & 3) * 8;
    const unsigned short* aSrc0 = Abf + (size_t)(r0 + lrow0) * DIMD + kof;
    const unsigned short* aSrc1 = aSrc0 + (size_t)16 * DIMD;
    const unsigned short* bSrc0 = Wbf + (size_t)(c0 + lrow0) * DIMD + kof;
    const unsigned short* bSrc1 = bSrc0 + (size_t)16 * DIMD;
    unsigned short* aDst0 = &As[0][inst0 * 512];
    unsigned short* aDst1 = &As[0][(inst0 + 1) * 512];
    unsigned short* bDst0 = &Bs[0][inst0 * 512];
    unsigned short* bDst1 = &Bs[0][(inst0 + 1) * 512];

    f32x4 acc[4][4];
    #pragma unroll
    for (int mi = 0; mi < 4; ++mi)
        #pragma unroll
        for (int ni = 0; ni < 4; ++ni) acc[mi][ni] = (f32x4){0.f, 0.f, 0.f, 0.f};

    // prologue: stage chunk 0 into buf 0
    gload16(aSrc0, aDst0); gload16(aSrc1, aDst1);
    gload16(bSrc0, bDst0); gload16(bSrc1, bDst1);

    int cur = 0;
    for (int kc = 0; kc < 16; ++kc) {
        __syncthreads();   // drains vmcnt: buf[cur] staged & visible
        if (kc + 1 < 16) {
            const int nb = cur ^ 1;
            const int ke = (kc + 1) * 32;
            gload16(aSrc0 + ke, &As[nb][inst0 * 512]);
            gload16(aSrc1 + ke, &As[nb][(inst0 + 1) * 512]);
            gload16(bSrc0 + ke, &Bs[nb][inst0 * 512]);
            gload16(bSrc1 + ke, &Bs[nb][(inst0 + 1) * 512]);
        }
        const int ko = (lane >> 4) * 8;
        short8 a[4], b[4];
        #pragma unroll
        for (int mi = 0; mi < 4; ++mi)
            a[mi] = *(const short8*)&As[cur][(wm * 64 + mi * 16 + (lane & 15)) * 32 + ko];
        #pragma unroll
        for (int ni = 0; ni < 4; ++ni)
            b[ni] = *(const short8*)&Bs[cur][(wn * 64 + ni * 16 + (lane & 15)) * 32 + ko];
        #pragma unroll
        for (int mi = 0; mi < 4; ++mi)
            #pragma unroll
            for (int ni = 0; ni < 4; ++ni)
                acc[mi][ni] = __builtin_amdgcn_mfma_f32_16x16x32_bf16(a[mi], b[ni], acc[mi][ni], 0, 0, 0);
        __syncthreads();
        cur ^= 1;
    }

    // epilogue. C/D layout (m89-verified): col = lane&15, row = (lane>>4)*4 + reg
    float wsqv[4];
    #pragma unroll
    for (int ni = 0; ni < 4; ++ni)
        wsqv[ni] = wsq[c0 + wn * 64 + ni * 16 + (lane & 15)];

    if (PASS == 0) {
        #pragma unroll
        for (int mi = 0; mi < 4; ++mi) {
            #pragma unroll
            for (int reg = 0; reg < 4; ++reg) {
                float m = INFINITY;
                #pragma unroll
                for (int ni = 0; ni < 4; ++ni)
                    m = fminf(m, wsqv[ni] - 2.0f * acc[mi][ni][reg]);
                #pragma unroll
                for (int s = 1; s < 16; s <<= 1)
                    m = fminf(m, __shfl_xor(m, s, 64));
                if ((lane & 15) == 0)
                    aux_lds[wn * 128 + wm * 64 + mi * 16 + (lane >> 4) * 4 + reg] = m;
            }
        }
        __syncthreads();
        if (t < 128)
            partmin[(size_t)(r0 + t) * 64 + ct] = fminf(aux_lds[t], aux_lds[128 + t]);
    } else {
        #pragma unroll
        for (int mi = 0; mi < 4; ++mi) {
            #pragma unroll
            for (int reg = 0; reg < 4; ++reg) {
                const int row_l = wm * 64 + mi * 16 + (lane >> 4) * 4 + reg;
                const float thr = aux_lds[row_l];
                #pragma unroll
                for (int ni = 0; ni < 4; ++ni) {
                    const float d = wsqv[ni] - 2.0f * acc[mi][ni][reg];
                    if (d <= thr) {
                        const unsigned k = c0 + wn * 64 + ni * 16 + (lane & 15);
                        const unsigned pk = ((unsigned)(r0 + row_l) << 13) | k;
                        const unsigned ix = atomicAdd(gcount, 1u);
                        if (ix < CAP) list[ix] = pk;
                    }
                }
            }
        }
    }
}

__global__ __launch_bounds__(256) void rowmerge_k(const float* __restrict__ partmin,
                                                  float* __restrict__ rowmin)
{
    const int r = blockIdx.x * 256 + threadIdx.x;
    const float4* p = (const float4*)(partmin + (size_t)r * 64);
    float m = INFINITY;
    #pragma unroll
    for (int i = 0; i < 16; ++i) {
        float4 v = p[i];
        m = fminf(m, fminf(fminf(v.x, v.y), fminf(v.z, v.w)));
    }
    rowmin[r] = m;
}

// fp64-exact refine of candidates; reproduces round-1's formula bit-for-bit:
// dist = fl32( fl32(xsq+wsq) - 2*fl32(exact_dot) ), lexicographic (dist, k) min.
__global__ __launch_bounds__(256) void refine_k(const float* __restrict__ A,
                                                const float* __restrict__ W,
                                                const float* __restrict__ xsq,
                                                const float* __restrict__ wsq,
                                                const unsigned* __restrict__ list,
                                                const unsigned* __restrict__ gcount,
                                                unsigned long long* __restrict__ res)
{
    const int lane = threadIdx.x & 63;
    const int wid  = (blockIdx.x * 256 + threadIdx.x) >> 6;
    const int nw   = (gridDim.x * 256) >> 6;
    unsigned n = *gcount;
    if (n > CAP) n = CAP;
    for (unsigned i = wid; i < n; i += nw) {
        const unsigned pk = list[i];
        const unsigned row = pk >> 13, k = pk & 8191u;
        const float4* xp = (const float4*)(A + (size_t)row * DIMD);
        const float4* wp = (const float4*)(W + (size_t)k * DIMD);
        const float4 x0 = xp[lane * 2], x1 = xp[lane * 2 + 1];
        const float4 w0 = wp[lane * 2], w1 = wp[lane * 2 + 1];
        double s = (double)x0.x * w0.x + (double)x0.y * w0.y
                 + (double)x0.z * w0.z + (double)x0.w * w0.w
                 + (double)x1.x * w1.x + (double)x1.y * w1.y
                 + (double)x1.z * w1.z + (double)x1.w * w1.w;
        #pragma unroll
        for (int m = 1; m < 64; m <<= 1) s += __shfl_xor(s, m, 64);
        if (lane == 0) {
            const float Df = (float)s;
            const float dist = (xsq[row] + wsq[k]) - 2.0f * Df;
            const unsigned long long p =
                ((unsigned long long)__float_as_uint(dist) << 32) | (unsigned long long)k;
            atomicMin(res + row, p);
        }
    }
}

__global__ __launch_bounds__(256) void finish_k(const unsigned long long* __restrict__ res,
                                                int* __restrict__ idxo,
                                                float* __restrict__ out_ids)
{
    const int r = blockIdx.x * 256 + threadIdx.x;
    const int id = (int)(res[r] & 8191ull);
    idxo[r] = id;
    out_ids[r] = (float)id;
}

// ===================== fallback path (round-1 fp64 kernel, passes but slow) =====================

__global__ __launch_bounds__(512) void vqmain_k(const float* __restrict__ A,
                                                const float* __restrict__ W,
                                                const float* __restrict__ xsq,
                                                const float* __restrict__ wsq,
                                                float* __restrict__ partm,
                                                int* __restrict__ parti)
{
    __shared__ double As[32][128];
    __shared__ double Bs[32][64];

    const int t   = threadIdx.x;
    const int tx  = t & 15;
    const int ty  = t >> 4;
    const int r0  = blockIdx.x * 128;
    const int kbase = blockIdx.y * 4096;

    const int a_row = t & 127;
    const int a_d   = (t >> 7) << 2;
    const int w_row = t & 63;
    const int w_d   = (t >> 6) << 2;

    const float* Abase = A + (size_t)(r0 + a_row) * DIMD + a_d;

    float xs[4];
    #pragma unroll
    for (int i = 0; i < 4; ++i) xs[i] = xsq[r0 + ty * 4 + i];

    float mbest[4]; int ibest[4];
    #pragma unroll
    for (int i = 0; i < 4; ++i) { mbest[i] = INFINITY; ibest[i] = 0; }

    float4 av0 = *(const float4*)(Abase);
    float4 av1 = *(const float4*)(Abase + 16);
    float4 wv  = *(const float4*)(W + (size_t)(kbase + w_row) * DIMD + w_d);

    for (int kt = 0; kt < 64; ++kt) {
        double acc[4][4];
        #pragma unroll
        for (int i = 0; i < 4; ++i)
            #pragma unroll
            for (int jj = 0; jj < 4; ++jj) acc[i][jj] = 0.0;

        for (int dc = 0; dc < 16; ++dc) {
            __syncthreads();
            As[a_d + 0][a_row]  = (double)av0.x;
            As[a_d + 1][a_row]  = (double)av0.y;
            As[a_d + 2][a_row]  = (double)av0.z;
            As[a_d + 3][a_row]  = (double)av0.w;
            As[a_d + 16][a_row] = (double)av1.x;
            As[a_d + 17][a_row] = (double)av1.y;
            As[a_d + 18][a_row] = (double)av1.z;
            As[a_d + 19][a_row] = (double)av1.w;
            Bs[w_d + 0][w_row]  = (double)wv.x;
            Bs[w_d + 1][w_row]  = (double)wv.y;
            Bs[w_d + 2][w_row]  = (double)wv.z;
            Bs[w_d + 3][w_row]  = (double)wv.w;
            __syncthreads();

            int ndc = dc + 1, nkt = kt;
            if (ndc == 16) { ndc = 0; ++nkt; }
            if (nkt < 64) {
                av0 = *(const float4*)(Abase + ndc * 32);
                av1 = *(const float4*)(Abase + ndc * 32 + 16);
                wv  = *(const float4*)(W + (size_t)(kbase + nkt * 64 + w_row) * DIMD + ndc * 32 + w_d);
            }

            #pragma unroll 8
            for (int d = 0; d < 32; ++d) {
                double2 a01 = *(const double2*)&As[d][ty * 4];
                double2 a23 = *(const double2*)&As[d][ty * 4 + 2];
                double2 b01 = *(const double2*)&Bs[d][tx * 4];
                double2 b23 = *(const double2*)&Bs[d][tx * 4 + 2];
                acc[0][0] += a01.x * b01.x;  acc[0][1] += a01.x * b01.y;
                acc[0][2] += a01.x * b23.x;  acc[0][3] += a01.x * b23.y;
                acc[1][0] += a01.y * b01.x;  acc[1][1] += a01.y * b01.y;
                acc[1][2] += a01.y * b23.x;  acc[1][3] += a01.y * b23.y;
                acc[2][0] += a23.x * b01.x;  acc[2][1] += a23.x * b01.y;
                acc[2][2] += a23.x * b23.x;  acc[2][3] += a23.x * b23.y;
                acc[3][0] += a23.y * b01.x;  acc[3][1] += a23.y * b01.y;
                acc[3][2] += a23.y * b23.x;  acc[3][3] += a23.y * b23.y;
            }
        }

        const int k0 = kbase + kt * 64;
        #pragma unroll
        for (int i = 0; i < 4; ++i) {
            #pragma unroll
            for (int jj = 0; jj < 4; ++jj) {
                const int k = k0 + tx * 4 + jj;
                const float Df = (float)acc[i][jj];
                const float dist = (xs[i] + wsq[k]) - 2.0f * Df;
                if (dist < mbest[i]) { mbest[i] = dist; ibest[i] = k; }
            }
        }
    }

    #pragma unroll
    for (int i = 0; i < 4; ++i) {
        float m = mbest[i]; int id = ibest[i];
        #pragma unroll
        for (int s = 1; s < 16; s <<= 1) {
            float om = __shfl_xor(m, s, 64);
            int   oi = __shfl_xor(id, s, 64);
            if (om < m || (om == m && oi < id)) { m = om; id = oi; }
        }
        if (tx == 0) {
            const int row = r0 + ty * 4 + i;
            partm[blockIdx.y * MROWS + row] = m;
            parti[blockIdx.y * MROWS + row] = id;
        }
    }
}

__global__ __launch_bounds__(256) void merge_k(const float* __restrict__ partm,
                                               const int* __restrict__ parti,
                                               int* __restrict__ idxo,
                                               float* __restrict__ out_ids)
{
    const int r = blockIdx.x * 256 + threadIdx.x;
    if (r >= MROWS) return;
    const float m0 = partm[r],       m1 = partm[MROWS + r];
    const int   i0 = parti[r],       i1 = parti[MROWS + r];
    const int id = (m1 < m0) ? i1 : i0;
    idxo[r] = id;
    out_ids[r] = (float)id;
}

// ===================== launch =====================

extern "C" void kernel_launch(void* const* d_in, const int* in_sizes, int n_in,
                              void* d_out, int out_size, void* d_ws, size_t ws_size,
                              hipStream_t stream)
{
    const float* A = (const float*)d_in[0];
    const float* W = (const float*)d_in[1];

    char* ws = (char*)d_ws;
    float* out_zq  = (float*)d_out;
    float* out_ids = out_zq + (size_t)MROWS * DIMD;
    float* out_sc  = out_ids + MROWS;

    if (ws_size >= (size_t)WS_NEEDED) {
        unsigned short* Abf   = (unsigned short*)(ws + OFF_ABF);
        unsigned short* Wbf   = (unsigned short*)(ws + OFF_WBF);
        float*  xsq     = (float*)(ws + OFF_XSQ);
        float*  wsq     = (float*)(ws + OFF_WSQ);
        float*  rowmin  = (float*)(ws + OFF_ROWMIN);
        float*  partmin = (float*)(ws + OFF_PARTMIN);
        unsigned long long* res = (unsigned long long*)(ws + OFF_RES);
        unsigned int* gcount    = (unsigned int*)(ws + OFF_CNT);
        unsigned int* list      = (unsigned int*)(ws + OFF_LIST);
        double* partial = (double*)(ws + OFF_PARTIAL);
        int*    idx     = (int*)(ws + OFF_IDX);

        init_k<<<64, 256, 0, stream>>>(res, gcount);
        cvt_k<<<2048, 256, 0, stream>>>(A, W, Abf, Wbf);
        sqnorms_k<<<512, 256, 0, stream>>>(A, W, xsq, wsq);
        vqgemm_k<0><<<8192, 256, 0, stream>>>(Abf, Wbf, wsq, rowmin, partmin, list, gcount);
        rowmerge_k<<<64, 256, 0, stream>>>(partmin, rowmin);
        vqgemm_k<1><<<8192, 256, 0, stream>>>(Abf, Wbf, wsq, rowmin, partmin, list, gcount);
        refine_k<<<512, 256, 0, stream>>>(A, W, xsq, wsq, list, gcount, res);
        finish_k<<<64, 256, 0, stream>>>(res, idx, out_ids);
        gather_k<<<8192, 256, 0, stream>>>(A, W, idx, out_zq, partial);
        fin_k<<<1, 256, 0, stream>>>(partial, out_sc);
    } else {
        // round-1 fp64 fallback (fits 491 KB ws)
        float*  xsq     = (float*)(ws);
        float*  wsq     = (float*)(ws + 65536);
        int*    idx     = (int*)  (ws + 98304);
        float*  partm   = (float*)(ws + 163840);
        int*    parti   = (int*)  (ws + 294912);
        double* partial = (double*)(ws + 425984);

        sqnorms_k<<<512, 256, 0, stream>>>(A, W, xsq, wsq);
        vqmain_k<<<dim3(128, 2), 512, 0, stream>>>(A, W, xsq, wsq, partm, parti);
        merge_k<<<64, 256, 0, stream>>>(partm, parti, idx, out_ids);
        gather_k<<<8192, 256, 0, stream>>>(A, W, idx, out_zq, partial);
        fin_k<<<1, 256, 0, stream>>>(partial, out_sc);
    }
}